// Round 1
// baseline (2027.258 us; speedup 1.0000x reference)
//
#include <hip/hip_runtime.h>

#define N_TOK 1024
#define NODE  384
#define PAIR  128
#define H     12
#define QKV_DIM 1152
#define OUT_CAT 2112
#define JT    32

// ws layout (floats)
#define OFF_NF   0
#define OFF_QKV  (OFF_NF  + N_TOK*NODE)      // 393216
#define OFF_GQP  (OFF_QKV + N_TOK*QKV_DIM)   // +1179648
#define OFF_GKP  (OFF_GQP + N_TOK*144)
#define OFF_GVP  (OFF_GKP + N_TOK*144)
#define OFF_Q2   (OFF_GVP + N_TOK*288)
#define OFF_K2   (OFF_Q2  + N_TOK*H)
#define OFF_X    (OFF_K2  + N_TOK*H)
// total = OFF_X + N_TOK*OUT_CAT = 4,349,952 floats = 17.4 MB

// ---------------------------------------------------------------- K1: node LN
__global__ void ln_node_kernel(const float* __restrict__ x, const float* __restrict__ g,
                               const float* __restrict__ b, float* __restrict__ y) {
    int n = blockIdx.x, t = threadIdx.x;  // 64 threads
    const float* row = x + (size_t)n * NODE;
    float v[6];
    float s = 0.f, q = 0.f;
#pragma unroll
    for (int w = 0; w < 6; ++w) { v[w] = row[t + 64*w]; s += v[w]; q += v[w]*v[w]; }
#pragma unroll
    for (int m = 1; m < 64; m <<= 1) { s += __shfl_xor(s, m, 64); q += __shfl_xor(q, m, 64); }
    float mean = s * (1.f/NODE);
    float var  = q * (1.f/NODE) - mean*mean;
    float rs   = rsqrtf(var + 1e-5f);
#pragma unroll
    for (int w = 0; w < 6; ++w) {
        int k = t + 64*w;
        y[(size_t)n*NODE + k] = (v[w]-mean)*rs*g[k] + b[k];
    }
}

// ------------------------------------------------- K2/K6: generic fp32 GEMM-NT
// C[M][N] = A[M][K] * B[N][K]^T (+ bias[n]); K % KC == 0, M % BM == 0, N % BN == 0
template<int BM, int BN, int TM, int TN, int KC>
__global__ void gemm_nt(const float* __restrict__ A, const float* __restrict__ B,
                        const float* __restrict__ bias, float* __restrict__ C,
                        int M, int N, int K) {
    constexpr int TX = BN / TN, TY = BM / TM;
    constexpr int THREADS = TX * TY;
    static_assert(BM * KC / 4 == THREADS && BN * KC / 4 == THREADS, "load mapping");
    __shared__ float As[KC][BM + 4];
    __shared__ float Bs[KC][BN + 4];
    const int t  = threadIdx.x;
    const int m0 = blockIdx.x * BM, n0 = blockIdx.y * BN;
    const int tn = t % TX, tm = t / TX;
    constexpr int LPR = KC / 4;
    const int lr = t / LPR, lk = t % LPR;
    float acc[TM][TN] = {};
    for (int k0 = 0; k0 < K; k0 += KC) {
        float4 a4 = *(const float4*)(A + (size_t)(m0 + lr) * K + k0 + lk*4);
        float4 b4 = *(const float4*)(B + (size_t)(n0 + lr) * K + k0 + lk*4);
        __syncthreads();
        As[lk*4+0][lr] = a4.x; As[lk*4+1][lr] = a4.y; As[lk*4+2][lr] = a4.z; As[lk*4+3][lr] = a4.w;
        Bs[lk*4+0][lr] = b4.x; Bs[lk*4+1][lr] = b4.y; Bs[lk*4+2][lr] = b4.z; Bs[lk*4+3][lr] = b4.w;
        __syncthreads();
#pragma unroll
        for (int k = 0; k < KC; ++k) {
            float a[TM], b[TN];
            if constexpr (TM == 4) { *(float4*)a = *(const float4*)&As[k][tm*TM]; }
            else                   { *(float2*)a = *(const float2*)&As[k][tm*TM]; }
            if constexpr (TN == 4) { *(float4*)b = *(const float4*)&Bs[k][tn*TN]; }
            else                   { *(float2*)b = *(const float2*)&Bs[k][tn*TN]; }
#pragma unroll
            for (int r = 0; r < TM; ++r)
#pragma unroll
                for (int c = 0; c < TN; ++c) acc[r][c] += a[r] * b[c];
        }
    }
#pragma unroll
    for (int r = 0; r < TM; ++r)
#pragma unroll
        for (int c = 0; c < TN; ++c) {
            int m = m0 + tm*TM + r, n = n0 + tn*TN + c;
            float o = acc[r][c] + (bias ? bias[n] : 0.f);
            C[(size_t)m * N + n] = o;
        }
}

// ----------------------------------------- K3: rigid-transform points, q2/k2
__global__ void prep_points(const float* __restrict__ qkv, const float* __restrict__ rot,
                            const float* __restrict__ trans,
                            float* __restrict__ gqp, float* __restrict__ gkp,
                            float* __restrict__ gvp, float* __restrict__ q2a,
                            float* __restrict__ k2a) {
    int n = blockIdx.x, t = threadIdx.x;  // 256 threads
    __shared__ float sq[144], sk[144];
    float R[9], T[3];
#pragma unroll
    for (int k = 0; k < 9; ++k) R[k] = rot[(size_t)n*9 + k];
#pragma unroll
    for (int c = 0; c < 3; ++c) T[c] = trans[(size_t)n*3 + c];
    const float* row = qkv + (size_t)n * QKV_DIM;
    if (t < 48) {               // q points
        int m = t;
        float x0 = row[576 + m*3], x1 = row[576 + m*3 + 1], x2 = row[576 + m*3 + 2];
#pragma unroll
        for (int r = 0; r < 3; ++r) {
            float g = R[r*3+0]*x0 + R[r*3+1]*x1 + R[r*3+2]*x2 + T[r];
            gqp[(size_t)n*144 + m*3 + r] = g; sq[m*3 + r] = g;
        }
    } else if (t < 96) {        // k points
        int m = t - 48;
        float x0 = row[720 + m*3], x1 = row[720 + m*3 + 1], x2 = row[720 + m*3 + 2];
#pragma unroll
        for (int r = 0; r < 3; ++r) {
            float g = R[r*3+0]*x0 + R[r*3+1]*x1 + R[r*3+2]*x2 + T[r];
            gkp[(size_t)n*144 + m*3 + r] = g; sk[m*3 + r] = g;
        }
    } else if (t < 192) {       // v points
        int m = t - 96;
        float x0 = row[864 + m*3], x1 = row[864 + m*3 + 1], x2 = row[864 + m*3 + 2];
#pragma unroll
        for (int r = 0; r < 3; ++r)
            gvp[(size_t)n*288 + m*3 + r] = R[r*3+0]*x0 + R[r*3+1]*x1 + R[r*3+2]*x2 + T[r];
    }
    __syncthreads();
    if (t < 12) {
        float s = 0.f;
#pragma unroll
        for (int u = 0; u < 12; ++u) { float g = sq[t*12 + u]; s += g*g; }
        q2a[(size_t)n*H + t] = s;
    } else if (t < 24) {
        int h = t - 12; float s = 0.f;
#pragma unroll
        for (int u = 0; u < 12; ++u) { float g = sk[h*12 + u]; s += g*g; }
        k2a[(size_t)n*H + h] = s;
    }
}

// -------------------------------------------------- K4: fused IPA attention
// 384 threads = 12 head-groups x 32 lanes; 2 queries per block (IT=2).
__global__ __launch_bounds__(384)
void ipa_attn(const float* __restrict__ pair, const float* __restrict__ lpg,
              const float* __restrict__ lpb, const float* __restrict__ wpb,
              const float* __restrict__ pw,  const float* __restrict__ qkv,
              const float* __restrict__ gqp, const float* __restrict__ q2a,
              const float* __restrict__ gkp, const float* __restrict__ k2a,
              const float* __restrict__ gvp, const float* __restrict__ rot,
              const float* __restrict__ trans, float* __restrict__ X) {
    __shared__ float s_pf[2][JT][132];   // LN'd pair tile, padded
    __shared__ float s_wpb[H][PAIR];
    __shared__ float s_g[PAIR], s_b[PAIR];

    const int t = threadIdx.x;
    const int h = t >> 5, q = t & 31;
    const int i0 = blockIdx.x * 2;

    ((float4*)s_wpb)[t] = ((const float4*)wpb)[t];          // 384*4 = 1536
    if (t < 32) {
        ((float4*)s_g)[t] = ((const float4*)lpg)[t];
        ((float4*)s_b)[t] = ((const float4*)lpb)[t];
    }

    // q-side registers (per head)
    float qs[2][16], qp[2][12], q2v[2];
#pragma unroll
    for (int i = 0; i < 2; ++i) {
        const float* qr = qkv + (size_t)(i0+i)*QKV_DIM + h*16;
#pragma unroll
        for (int d = 0; d < 16; ++d) qs[i][d] = qr[d];
        const float* pr = gqp + (size_t)(i0+i)*144 + h*12;
#pragma unroll
        for (int m = 0; m < 12; ++m) qp[i][m] = pr[m];
        q2v[i] = q2a[(size_t)(i0+i)*H + h];
    }
    const float spw = log1pf(__expf(pw[h]));
    const float SS  = 0.14433756729740643f;   // (3*16)^-0.5
    const float PSC = -0.08091538742f * spw;  // -(3*4*9*sqrt2)^-0.5 * softplus
    const float PB  = 0.5773502691896258f;    // 3^-0.5

    float m_[2] = { -3.0e38f, -3.0e38f };
    float l_[2] = { 0.f, 0.f };
    float accP[2][4] = {};
    float accS[2] = { 0.f, 0.f };
    float accT[2] = { 0.f, 0.f };

    for (int j0 = 0; j0 < N_TOK; j0 += JT) {
        __syncthreads();   // previous tile's pf fully consumed
        // ---- A: load + layernorm pair rows (64 rows, 8 lanes/row, 2 passes)
#pragma unroll
        for (int pass = 0; pass < 2; ++pass) {
            int row = pass*48 + (t >> 3);
            if (row < 64) {
                int i = row >> 5, jj = row & 31, lane = t & 7;
                const float* src = pair + ((size_t)(i0+i)*N_TOK + j0 + jj)*PAIR + lane*16;
                float f[16];
                *(float4*)&f[0]  = ((const float4*)src)[0];
                *(float4*)&f[4]  = ((const float4*)src)[1];
                *(float4*)&f[8]  = ((const float4*)src)[2];
                *(float4*)&f[12] = ((const float4*)src)[3];
                float s = 0.f, qq = 0.f;
#pragma unroll
                for (int k = 0; k < 16; ++k) { s += f[k]; qq += f[k]*f[k]; }
#pragma unroll
                for (int mm = 1; mm < 8; mm <<= 1) {
                    s  += __shfl_xor(s,  mm, 8);
                    qq += __shfl_xor(qq, mm, 8);
                }
                float mean = s * (1.f/128.f);
                float var  = qq * (1.f/128.f) - mean*mean;
                float rs   = rsqrtf(var + 1e-5f);
                float* dst = &s_pf[i][jj][lane*16];
#pragma unroll
                for (int k = 0; k < 16; ++k)
                    f[k] = (f[k]-mean)*rs*s_g[lane*16+k] + s_b[lane*16+k];
                ((float4*)dst)[0] = *(float4*)&f[0];
                ((float4*)dst)[1] = *(float4*)&f[4];
                ((float4*)dst)[2] = *(float4*)&f[8];
                ((float4*)dst)[3] = *(float4*)&f[12];
            }
        }
        __syncthreads();

        // ---- B: logits for my (h, jj=q), both queries
        float lg0, lg1;
        {
            const float4* wrow = (const float4*)&s_wpb[h][0];
            const float4* p0r  = (const float4*)&s_pf[0][q][0];
            const float4* p1r  = (const float4*)&s_pf[1][q][0];
            float bias0 = 0.f, bias1 = 0.f;
#pragma unroll 8
            for (int k = 0; k < 32; ++k) {
                float4 w = wrow[k], a = p0r[k], b = p1r[k];
                bias0 += w.x*a.x + w.y*a.y + w.z*a.z + w.w*a.w;
                bias1 += w.x*b.x + w.y*b.y + w.z*b.z + w.w*b.w;
            }
            int j = j0 + q;
            const float* kr = qkv + (size_t)j*QKV_DIM + 192 + h*16;
            float sl0 = 0.f, sl1 = 0.f;
#pragma unroll
            for (int d = 0; d < 16; ++d) { float kv = kr[d]; sl0 += qs[0][d]*kv; sl1 += qs[1][d]*kv; }
            const float* kpr = gkp + (size_t)j*144 + h*12;
            float qk0 = 0.f, qk1 = 0.f;
#pragma unroll
            for (int m = 0; m < 12; ++m) { float kv = kpr[m]; qk0 += qp[0][m]*kv; qk1 += qp[1][m]*kv; }
            float k2v = k2a[(size_t)j*H + h];
            float d0 = q2v[0] + k2v - 2.f*qk0;
            float d1 = q2v[1] + k2v - 2.f*qk1;
            lg0 = SS*sl0 + PSC*d0 + PB*bias0;
            lg1 = SS*sl1 + PSC*d1 + PB*bias1;
        }

        // ---- C: online softmax update per query (within 32-lane head group)
        float p0, p1;
        {
            float mx = lg0;
#pragma unroll
            for (int mm = 1; mm < 32; mm <<= 1) mx = fmaxf(mx, __shfl_xor(mx, mm, 32));
            float mnew = fmaxf(m_[0], mx);
            float al = __expf(m_[0] - mnew);
            p0 = __expf(lg0 - mnew);
            float s = p0;
#pragma unroll
            for (int mm = 1; mm < 32; mm <<= 1) s += __shfl_xor(s, mm, 32);
            l_[0] = l_[0]*al + s; m_[0] = mnew;
            accP[0][0]*=al; accP[0][1]*=al; accP[0][2]*=al; accP[0][3]*=al;
            accS[0]*=al; accT[0]*=al;
        }
        {
            float mx = lg1;
#pragma unroll
            for (int mm = 1; mm < 32; mm <<= 1) mx = fmaxf(mx, __shfl_xor(mx, mm, 32));
            float mnew = fmaxf(m_[1], mx);
            float al = __expf(m_[1] - mnew);
            p1 = __expf(lg1 - mnew);
            float s = p1;
#pragma unroll
            for (int mm = 1; mm < 32; mm <<= 1) s += __shfl_xor(s, mm, 32);
            l_[1] = l_[1]*al + s; m_[1] = mnew;
            accP[1][0]*=al; accP[1][1]*=al; accP[1][2]*=al; accP[1][3]*=al;
            accS[1]*=al; accT[1]*=al;
        }

        // ---- D: accumulate
        const float* vsbase = qkv + (size_t)j0*QKV_DIM + 384 + h*16 + q;  // valid use q<16
        const float* gvbase = gvp + (size_t)j0*288 + h*24 + q;            // valid use q<24
#pragma unroll 4
        for (int jj = 0; jj < JT; ++jj) {
            float pj0 = __shfl(p0, jj, 32);
            float pj1 = __shfl(p1, jj, 32);
            float4 a = *(const float4*)&s_pf[0][jj][q*4];
            float4 b = *(const float4*)&s_pf[1][jj][q*4];
            accP[0][0] += pj0*a.x; accP[0][1] += pj0*a.y; accP[0][2] += pj0*a.z; accP[0][3] += pj0*a.w;
            accP[1][0] += pj1*b.x; accP[1][1] += pj1*b.y; accP[1][2] += pj1*b.z; accP[1][3] += pj1*b.w;
            if (q < 16) { float v = vsbase[(size_t)jj*QKV_DIM]; accS[0] += pj0*v; accS[1] += pj1*v; }
            if (q < 24) { float g = gvbase[jj*288];             accT[0] += pj0*g; accT[1] += pj1*g; }
        }
    }

    // ---- Epilogue: finalize, inverse rigid, write concat vector X
#pragma unroll
    for (int i = 0; i < 2; ++i) {
        int n = i0 + i;
        float inv = 1.f / l_[i];
        float* Xr = X + (size_t)n * OUT_CAT;
        if (q < 16) Xr[h*16 + q] = accS[i]*inv;
        float4 pr;
        pr.x = accP[i][0]*inv; pr.y = accP[i][1]*inv; pr.z = accP[i][2]*inv; pr.w = accP[i][3]*inv;
        *(float4*)&Xr[576 + h*128 + q*4] = pr;

        float v = accT[i]*inv;                 // global-frame component (dp*3+c)
        int dp3 = (q/3)*3;
        float v0 = __shfl(v, dp3 + 0, 32);
        float v1 = __shfl(v, dp3 + 1, 32);
        float v2 = __shfl(v, dp3 + 2, 32);
        int r = q - dp3;
        float rp = rot[(size_t)n*9 + 0*3 + r]*(v0 - trans[(size_t)n*3 + 0])
                 + rot[(size_t)n*9 + 1*3 + r]*(v1 - trans[(size_t)n*3 + 1])
                 + rot[(size_t)n*9 + 2*3 + r]*(v2 - trans[(size_t)n*3 + 2]);
        if (q < 24) Xr[192 + h*24 + q] = rp;
        int s0 = (q < 8) ? q*3 : 0;
        float r0 = __shfl(rp, s0 + 0, 32);
        float r1 = __shfl(rp, s0 + 1, 32);
        float r2 = __shfl(rp, s0 + 2, 32);
        if (q < 8) Xr[480 + h*8 + q] = sqrtf(r0*r0 + r1*r1 + r2*r2 + 1e-8f);
    }
}

// ---------------------------------------------------------------------------
extern "C" void kernel_launch(void* const* d_in, const int* in_sizes, int n_in,
                              void* d_out, int out_size, void* d_ws, size_t ws_size,
                              hipStream_t stream) {
    const float* node  = (const float*)d_in[0];
    const float* rot   = (const float*)d_in[1];
    const float* trans = (const float*)d_in[2];
    const float* pair  = (const float*)d_in[3];
    // d_in[4] = mask (all true in this problem) — masking is a no-op, skipped
    const float* lsg  = (const float*)d_in[5];
    const float* lsb  = (const float*)d_in[6];
    const float* lpg  = (const float*)d_in[7];
    const float* lpb  = (const float*)d_in[8];
    const float* wpb  = (const float*)d_in[9];
    const float* wqkv = (const float*)d_in[10];
    const float* pw   = (const float*)d_in[11];
    const float* wout = (const float*)d_in[12];
    const float* bout = (const float*)d_in[13];

    float* ws  = (float*)d_ws;
    float* NF  = ws + OFF_NF;
    float* QKV = ws + OFF_QKV;
    float* GQP = ws + OFF_GQP;
    float* GKP = ws + OFF_GKP;
    float* GVP = ws + OFF_GVP;
    float* Q2  = ws + OFF_Q2;
    float* K2A = ws + OFF_K2;
    float* Xc  = ws + OFF_X;

    ln_node_kernel<<<N_TOK, 64, 0, stream>>>(node, lsg, lsb, NF);
    gemm_nt<64,64,4,4,16><<<dim3(N_TOK/64, QKV_DIM/64), 256, 0, stream>>>(
        NF, wqkv, nullptr, QKV, N_TOK, QKV_DIM, NODE);
    prep_points<<<N_TOK, 256, 0, stream>>>(QKV, rot, trans, GQP, GKP, GVP, Q2, K2A);
    ipa_attn<<<N_TOK/2, 384, 0, stream>>>(pair, lpg, lpb, wpb, pw, QKV,
                                          GQP, Q2, GKP, K2A, GVP, rot, trans, Xc);
    gemm_nt<32,32,2,2,32><<<dim3(N_TOK/32, NODE/32), 256, 0, stream>>>(
        Xc, wout, bout, (float*)d_out, N_TOK, NODE, OUT_CAT);
}

// Round 2
// 1725.006 us; speedup vs baseline: 1.1752x; 1.1752x over previous
//
#include <hip/hip_runtime.h>

#define N_TOK 1024
#define NODE  384
#define PAIR  128
#define H     12
#define QKV_DIM 1152
#define OUT_CAT 2112

// ws layout (floats)
#define OFF_NF   0
#define OFF_QKV  (OFF_NF  + N_TOK*NODE)
#define OFF_GQP  (OFF_QKV + N_TOK*QKV_DIM)
#define OFF_GKP  (OFF_GQP + N_TOK*144)
#define OFF_GVP  (OFF_GKP + N_TOK*144)
#define OFF_Q2   (OFF_GVP + N_TOK*288)
#define OFF_K2   (OFF_Q2  + N_TOK*H)
#define OFF_X    (OFF_K2  + N_TOK*H)

typedef __attribute__((ext_vector_type(8))) short s8v;
typedef __attribute__((ext_vector_type(4))) float f4a;

static __device__ __forceinline__ unsigned short f2b(float x) {
    unsigned u = __builtin_bit_cast(unsigned, x);
    unsigned r = (u + 0x7FFF + ((u >> 16) & 1)) >> 16;
    return (unsigned short)r;
}

// ---------------------------------------------------------------- K1: node LN
__global__ void ln_node_kernel(const float* __restrict__ x, const float* __restrict__ g,
                               const float* __restrict__ b, float* __restrict__ y) {
    int n = blockIdx.x, t = threadIdx.x;  // 64 threads
    const float* row = x + (size_t)n * NODE;
    float v[6];
    float s = 0.f, q = 0.f;
#pragma unroll
    for (int w = 0; w < 6; ++w) { v[w] = row[t + 64*w]; s += v[w]; q += v[w]*v[w]; }
#pragma unroll
    for (int m = 1; m < 64; m <<= 1) { s += __shfl_xor(s, m, 64); q += __shfl_xor(q, m, 64); }
    float mean = s * (1.f/NODE);
    float var  = q * (1.f/NODE) - mean*mean;
    float rs   = rsqrtf(var + 1e-5f);
#pragma unroll
    for (int w = 0; w < 6; ++w) {
        int k = t + 64*w;
        y[(size_t)n*NODE + k] = (v[w]-mean)*rs*g[k] + b[k];
    }
}

// ------------------------------------------------- generic fp32 GEMM-NT
template<int BM, int BN, int TM, int TN, int KC>
__global__ void gemm_nt(const float* __restrict__ A, const float* __restrict__ B,
                        const float* __restrict__ bias, float* __restrict__ C,
                        int M, int N, int K) {
    constexpr int TX = BN / TN, TY = BM / TM;
    constexpr int THREADS = TX * TY;
    static_assert(BM * KC / 4 == THREADS && BN * KC / 4 == THREADS, "load mapping");
    __shared__ float As[KC][BM + 4];
    __shared__ float Bs[KC][BN + 4];
    const int t  = threadIdx.x;
    const int m0 = blockIdx.x * BM, n0 = blockIdx.y * BN;
    const int tn = t % TX, tm = t / TX;
    constexpr int LPR = KC / 4;
    const int lr = t / LPR, lk = t % LPR;
    float acc[TM][TN] = {};
    for (int k0 = 0; k0 < K; k0 += KC) {
        float4 a4 = *(const float4*)(A + (size_t)(m0 + lr) * K + k0 + lk*4);
        float4 b4 = *(const float4*)(B + (size_t)(n0 + lr) * K + k0 + lk*4);
        __syncthreads();
        As[lk*4+0][lr] = a4.x; As[lk*4+1][lr] = a4.y; As[lk*4+2][lr] = a4.z; As[lk*4+3][lr] = a4.w;
        Bs[lk*4+0][lr] = b4.x; Bs[lk*4+1][lr] = b4.y; Bs[lk*4+2][lr] = b4.z; Bs[lk*4+3][lr] = b4.w;
        __syncthreads();
#pragma unroll
        for (int k = 0; k < KC; ++k) {
            float a[TM], b[TN];
            if constexpr (TM == 4) { *(float4*)a = *(const float4*)&As[k][tm*TM]; }
            else                   { *(float2*)a = *(const float2*)&As[k][tm*TM]; }
            if constexpr (TN == 4) { *(float4*)b = *(const float4*)&Bs[k][tn*TN]; }
            else                   { *(float2*)b = *(const float2*)&Bs[k][tn*TN]; }
#pragma unroll
            for (int r = 0; r < TM; ++r)
#pragma unroll
                for (int c = 0; c < TN; ++c) acc[r][c] += a[r] * b[c];
        }
    }
#pragma unroll
    for (int r = 0; r < TM; ++r)
#pragma unroll
        for (int c = 0; c < TN; ++c) {
            int m = m0 + tm*TM + r, n = n0 + tn*TN + c;
            float o = acc[r][c] + (bias ? bias[n] : 0.f);
            C[(size_t)m * N + n] = o;
        }
}

// ----------------------------------------- K3: rigid-transform points, q2/k2
__global__ void prep_points(const float* __restrict__ qkv, const float* __restrict__ rot,
                            const float* __restrict__ trans,
                            float* __restrict__ gqp, float* __restrict__ gkp,
                            float* __restrict__ gvp, float* __restrict__ q2a,
                            float* __restrict__ k2a) {
    int n = blockIdx.x, t = threadIdx.x;  // 256 threads
    __shared__ float sq[144], sk[144];
    float R[9], T[3];
#pragma unroll
    for (int k = 0; k < 9; ++k) R[k] = rot[(size_t)n*9 + k];
#pragma unroll
    for (int c = 0; c < 3; ++c) T[c] = trans[(size_t)n*3 + c];
    const float* row = qkv + (size_t)n * QKV_DIM;
    if (t < 48) {
        int m = t;
        float x0 = row[576 + m*3], x1 = row[576 + m*3 + 1], x2 = row[576 + m*3 + 2];
#pragma unroll
        for (int r = 0; r < 3; ++r) {
            float g = R[r*3+0]*x0 + R[r*3+1]*x1 + R[r*3+2]*x2 + T[r];
            gqp[(size_t)n*144 + m*3 + r] = g; sq[m*3 + r] = g;
        }
    } else if (t < 96) {
        int m = t - 48;
        float x0 = row[720 + m*3], x1 = row[720 + m*3 + 1], x2 = row[720 + m*3 + 2];
#pragma unroll
        for (int r = 0; r < 3; ++r) {
            float g = R[r*3+0]*x0 + R[r*3+1]*x1 + R[r*3+2]*x2 + T[r];
            gkp[(size_t)n*144 + m*3 + r] = g; sk[m*3 + r] = g;
        }
    } else if (t < 192) {
        int m = t - 96;
        float x0 = row[864 + m*3], x1 = row[864 + m*3 + 1], x2 = row[864 + m*3 + 2];
#pragma unroll
        for (int r = 0; r < 3; ++r)
            gvp[(size_t)n*288 + m*3 + r] = R[r*3+0]*x0 + R[r*3+1]*x1 + R[r*3+2]*x2 + T[r];
    }
    __syncthreads();
    if (t < 12) {
        float s = 0.f;
#pragma unroll
        for (int u = 0; u < 12; ++u) { float g = sq[t*12 + u]; s += g*g; }
        q2a[(size_t)n*H + t] = s;
    } else if (t < 24) {
        int h = t - 12; float s = 0.f;
#pragma unroll
        for (int u = 0; u < 12; ++u) { float g = sk[h*12 + u]; s += g*g; }
        k2a[(size_t)n*H + h] = s;
    }
}

// -------------------------------------------------- K4: fused IPA attention (MFMA)
// 512 threads = 8 waves; 2 queries/block; j-tiles of 64; all 12 heads.
__global__ __launch_bounds__(512, 4)
void ipa_attn2(const float* __restrict__ pair, const float* __restrict__ lpg,
               const float* __restrict__ lpb, const float* __restrict__ wpb,
               const float* __restrict__ pw,  const float* __restrict__ qkv,
               const float* __restrict__ gqp, const float* __restrict__ q2a,
               const float* __restrict__ gkp, const float* __restrict__ k2a,
               const float* __restrict__ gvp, const float* __restrict__ rot,
               const float* __restrict__ trans, float* __restrict__ X) {
    // LDS (64,128 B total)
    __shared__ __align__(16) unsigned short s_pf[128][136]; // LN'd pf, bf16, XOR-swizzled chunks
    __shared__ __align__(16) unsigned short s_at[2][16][72]; // attn bf16 (A-operand for res_pair)
    __shared__ __align__(16) float s_af[2][12][68];          // attn fp32 (for accS/accT)
    __shared__ __align__(16) float s_lgb[128][21];           // pair-bias logits (union: s_pt epilogue)
    __shared__ float s_alpha[2][16];
    __shared__ float s_linv[2][16];
    __shared__ __align__(16) float s_q[2][12][32];           // q_s[16], gqp[12], q2[1]
    __shared__ __align__(16) unsigned short s_wf[4][64][8];  // W_pb B-frags per lane

    const int t    = threadIdx.x;
    const int lane = t & 63, w = t >> 6;
    const int quad = (t >> 4) & 3, nn = t & 15;
    const int i0   = blockIdx.x * 2;

    const float SS = 0.14433756729740643f;   // (3*16)^-0.5
    const float PB = 0.5773502691896258f;    // 3^-0.5

    // ---- startup staging
    for (int idx = t; idx < 696; idx += 512) {
        int pp = idx / 29, e = idx % 29;
        int i = pp / 12, h = pp % 12;
        float v;
        if (e < 16)      v = qkv[(size_t)(i0+i)*QKV_DIM + h*16 + e];
        else if (e < 28) v = gqp[(size_t)(i0+i)*144 + h*12 + (e-16)];
        else             v = q2a[(size_t)(i0+i)*H + h];
        s_q[i][h][e] = v;
    }
    if (t < 64) {
        int qd = t >> 4, hq = t & 15;
#pragma unroll
        for (int k = 0; k < 4; ++k) {
            s8v v;
#pragma unroll
            for (int e = 0; e < 8; ++e) {
                int d = k*32 + qd*8 + e;
                float x = (hq < 12) ? wpb[hq*128 + d] : 0.f;
                v[e] = (short)f2b(x);
            }
            *(s8v*)&s_wf[k][t][0] = v;
        }
    }

    // B2 per-wave pair assignment: pairs p = 3w+c, h = p>>1, i = p&1
    int pc_h[3], pc_i[3];
    float pscv[3];
#pragma unroll
    for (int c = 0; c < 3; ++c) {
        int p = w*3 + c;
        pc_h[c] = p >> 1; pc_i[c] = p & 1;
        float sp = log1pf(__expf(pw[pc_h[c]]));
        pscv[c] = -0.08091538742f * sp;      // -(3*4*9*sqrt2)^-0.5 * softplus
    }
    float mC[3] = {-3.0e38f, -3.0e38f, -3.0e38f};
    float lC[3] = {0.f, 0.f, 0.f};

    // D2 (accS/accT) mapping
    const int hh = (t < 480) ? t / 40 : 0;
    const int dd = (t < 480) ? t % 40 : 0;
    const float* vbase = (dd < 16) ? (qkv + 384 + hh*16 + dd)
                                   : (gvp + hh*24 + (dd-16));
    const int vstr = (dd < 16) ? QKV_DIM : 288;
    float sA0 = 0.f, sA1 = 0.f;

    // res_pair mapping: wave w -> i_r = w&1, ntiles {w>>1, (w>>1)+4}
    const int i_r = w & 1, nt0 = w >> 1;
    f4a accR[2] = {{0.f,0.f,0.f,0.f},{0.f,0.f,0.f,0.f}};

    // phase A mapping
    const int rowA = t >> 2, l4 = t & 3;
    const int ipA = rowA >> 6, jjA = rowA & 63;
    const int mswA = (rowA >> 3) & 7;

    for (int j0 = 0; j0 < N_TOK; j0 += 64) {
        // ---- A: load + LN + bf16 + swizzled store
        {
            const float* src = pair + ((size_t)(i0 + ipA)*N_TOK + (j0 + jjA))*PAIR + l4*32;
            float f[32];
#pragma unroll
            for (int u = 0; u < 8; ++u) *(float4*)&f[u*4] = *(const float4*)&src[u*4];
            float s = 0.f, qq = 0.f;
#pragma unroll
            for (int u = 0; u < 32; ++u) { s += f[u]; qq += f[u]*f[u]; }
            s  += __shfl_xor(s, 1, 4);  s  += __shfl_xor(s, 2, 4);
            qq += __shfl_xor(qq, 1, 4); qq += __shfl_xor(qq, 2, 4);
            float mean = s * (1.f/128.f);
            float var  = qq * (1.f/128.f) - mean*mean;
            float rs   = rsqrtf(var + 1e-5f);
#pragma unroll
            for (int w2 = 0; w2 < 4; ++w2) {
                int c = l4*4 + w2;
                float4 g0 = *(const float4*)&lpg[c*8], g1 = *(const float4*)&lpg[c*8+4];
                float4 b0 = *(const float4*)&lpb[c*8], b1 = *(const float4*)&lpb[c*8+4];
                float gg[8] = {g0.x,g0.y,g0.z,g0.w,g1.x,g1.y,g1.z,g1.w};
                float bb[8] = {b0.x,b0.y,b0.z,b0.w,b1.x,b1.y,b1.z,b1.w};
                s8v v;
#pragma unroll
                for (int e = 0; e < 8; ++e) {
                    float y = (f[w2*8 + e] - mean)*rs*gg[e] + bb[e];
                    v[e] = (short)f2b(y);
                }
                *(s8v*)&s_pf[rowA][((c ^ mswA) << 3)] = v;
            }
        }
        __syncthreads();  // B1: pf ready

        // ---- bias MFMA (waves 0-3): lgb[row][h] = pf . W_pb^T
        if (w < 4) {
#pragma unroll
            for (int mi = 0; mi < 2; ++mi) {
                int mt = w + mi*4;
                int row = mt*16 + nn;
                int msw = (row >> 3) & 7;
                f4a acc = {0.f,0.f,0.f,0.f};
#pragma unroll
                for (int k = 0; k < 4; ++k) {
                    s8v a  = *(const s8v*)&s_pf[row][(((k*4 + quad) ^ msw) << 3)];
                    s8v wf = *(const s8v*)&s_wf[k][lane][0];
                    acc = __builtin_amdgcn_mfma_f32_16x16x32_bf16(a, wf, acc, 0, 0, 0);
                }
#pragma unroll
                for (int r = 0; r < 4; ++r)
                    s_lgb[mt*16 + quad*4 + r][nn] = acc[r];
            }
        }

        // ---- B2: scalar + point logits (all waves, regs only)
        float lg[3];
        {
            int hprev = -1;
            float ks[16], kpv[12], k2v = 0.f;
            const int jg = j0 + lane;
#pragma unroll
            for (int c = 0; c < 3; ++c) {
                const int hc = pc_h[c], ic = pc_i[c];
                if (hc != hprev) {
                    const float* kr = qkv + (size_t)jg*QKV_DIM + 192 + hc*16;
                    *(float4*)&ks[0]  = *(const float4*)&kr[0];
                    *(float4*)&ks[4]  = *(const float4*)&kr[4];
                    *(float4*)&ks[8]  = *(const float4*)&kr[8];
                    *(float4*)&ks[12] = *(const float4*)&kr[12];
                    const float* pr = gkp + (size_t)jg*144 + hc*12;
                    *(float4*)&kpv[0] = *(const float4*)&pr[0];
                    *(float4*)&kpv[4] = *(const float4*)&pr[4];
                    *(float4*)&kpv[8] = *(const float4*)&pr[8];
                    k2v = k2a[(size_t)jg*H + hc];
                    hprev = hc;
                }
                const float* qv = &s_q[ic][hc][0];
                float sl = 0.f;
#pragma unroll
                for (int d = 0; d < 16; ++d) sl += qv[d]*ks[d];
                float qk = 0.f;
#pragma unroll
                for (int m = 0; m < 12; ++m) qk += qv[16+m]*kpv[m];
                float d2 = qv[28] + k2v - 2.f*qk;
                lg[c] = SS*sl + pscv[c]*d2;
            }
        }
        __syncthreads();  // B2: lgb ready

        // ---- softmax (online, per (h,i) owned by this wave)
#pragma unroll
        for (int c = 0; c < 3; ++c) {
            const int hc = pc_h[c], ic = pc_i[c];
            float L = lg[c] + PB * s_lgb[ic*64 + lane][hc];
            float mx = L;
#pragma unroll
            for (int m = 1; m < 64; m <<= 1) mx = fmaxf(mx, __shfl_xor(mx, m, 64));
            float mnew = fmaxf(mC[c], mx);
            float al = __expf(mC[c] - mnew);
            float p  = __expf(L - mnew);
            float sm = p;
#pragma unroll
            for (int m = 1; m < 64; m <<= 1) sm += __shfl_xor(sm, m, 64);
            lC[c] = lC[c]*al + sm;
            mC[c] = mnew;
            s_at[ic][hc][lane] = f2b(p);
            s_af[ic][hc][lane] = p;
            if (lane == 0) s_alpha[ic][hc] = al;
        }
        __syncthreads();  // B3: attn ready

        // ---- D: res_pair MFMA  C[h][d] += attn[h][j] * pf[j][d]
        {
            float4 al4 = *(const float4*)&s_alpha[i_r][quad*4];
            accR[0][0]*=al4.x; accR[0][1]*=al4.y; accR[0][2]*=al4.z; accR[0][3]*=al4.w;
            accR[1][0]*=al4.x; accR[1][1]*=al4.y; accR[1][2]*=al4.z; accR[1][3]*=al4.w;
            s8v af0 = *(const s8v*)&s_at[i_r][nn][quad*8];
            s8v af1 = *(const s8v*)&s_at[i_r][nn][32 + quad*8];
#pragma unroll
            for (int idx = 0; idx < 2; ++idx) {
                int d = (nt0 + idx*4)*16 + nn;
                int ch = d >> 3, dl = d & 7;
#pragma unroll
                for (int s_ = 0; s_ < 2; ++s_) {
                    int msw = (s_*4 + quad) & 7;
                    const unsigned short* bp =
                        &s_pf[i_r*64 + s_*32 + quad*8][((ch ^ msw) << 3) | dl];
                    s8v bf;
#pragma unroll
                    for (int e = 0; e < 8; ++e) bf[e] = (short)bp[e*136];
                    accR[idx] = __builtin_amdgcn_mfma_f32_16x16x32_bf16(
                        (s_ == 0 ? af0 : af1), bf, accR[idx], 0, 0, 0);
                }
            }
        }
        // ---- D2: accS / accT (fp32)
        if (t < 480) {
            float a0 = s_alpha[0][hh], a1 = s_alpha[1][hh];
            sA0 *= a0; sA1 *= a1;
            const float* vr = vbase + (size_t)j0 * vstr;
#pragma unroll 4
            for (int jb = 0; jb < 16; ++jb) {
                float4 p0 = *(const float4*)&s_af[0][hh][jb*4];
                float4 p1 = *(const float4*)&s_af[1][hh][jb*4];
                float v0 = vr[(jb*4+0)*vstr];
                float v1 = vr[(jb*4+1)*vstr];
                float v2 = vr[(jb*4+2)*vstr];
                float v3 = vr[(jb*4+3)*vstr];
                sA0 += p0.x*v0 + p0.y*v1 + p0.z*v2 + p0.w*v3;
                sA1 += p1.x*v0 + p1.y*v1 + p1.z*v2 + p1.w*v3;
            }
        }
        __syncthreads();  // B4: consumers done before next tile overwrites
    }

    // ---- epilogue
#pragma unroll
    for (int c = 0; c < 3; ++c)
        if (lane == 0) s_linv[pc_i[c]][pc_h[c]] = 1.f / lC[c];
    __syncthreads();

    float* s_ptf = &s_lgb[0][0];   // union: s_pt[2][12][24]
    if (t < 480) {
        float li0 = s_linv[0][hh], li1 = s_linv[1][hh];
        if (dd < 16) {
            X[(size_t)i0*OUT_CAT + hh*16 + dd]     = sA0*li0;
            X[(size_t)(i0+1)*OUT_CAT + hh*16 + dd] = sA1*li1;
        } else {
            s_ptf[(0*12 + hh)*24 + (dd-16)] = sA0*li0;
            s_ptf[(12  + hh)*24 + (dd-16)] = sA1*li1;
        }
    }
    {
        float4 li4 = *(const float4*)&s_linv[i_r][quad*4];
        float liarr[4] = {li4.x, li4.y, li4.z, li4.w};
#pragma unroll
        for (int idx = 0; idx < 2; ++idx) {
            int dcol = (nt0 + idx*4)*16 + nn;
#pragma unroll
            for (int r = 0; r < 4; ++r) {
                int h = quad*4 + r;
                if (h < 12)
                    X[(size_t)(i0+i_r)*OUT_CAT + 576 + h*128 + dcol] = accR[idx][r]*liarr[r];
            }
        }
    }
    __syncthreads();
    if (t < 192) {
        int i = t / 96, rem = t % 96, h = rem >> 3, dp = rem & 7;
        int n = i0 + i;
        float v0 = s_ptf[(i*12+h)*24 + dp*3 + 0] - trans[n*3+0];
        float v1 = s_ptf[(i*12+h)*24 + dp*3 + 1] - trans[n*3+1];
        float v2 = s_ptf[(i*12+h)*24 + dp*3 + 2] - trans[n*3+2];
        float r0 = rot[n*9+0]*v0 + rot[n*9+3]*v1 + rot[n*9+6]*v2;
        float r1 = rot[n*9+1]*v0 + rot[n*9+4]*v1 + rot[n*9+7]*v2;
        float r2 = rot[n*9+2]*v0 + rot[n*9+5]*v1 + rot[n*9+8]*v2;
        float* Xr = X + (size_t)n*OUT_CAT;
        Xr[192 + h*24 + dp*3 + 0] = r0;
        Xr[192 + h*24 + dp*3 + 1] = r1;
        Xr[192 + h*24 + dp*3 + 2] = r2;
        Xr[480 + h*8 + dp] = sqrtf(r0*r0 + r1*r1 + r2*r2 + 1e-8f);
    }
}

// ---------------------------------------------------------------------------
extern "C" void kernel_launch(void* const* d_in, const int* in_sizes, int n_in,
                              void* d_out, int out_size, void* d_ws, size_t ws_size,
                              hipStream_t stream) {
    const float* node  = (const float*)d_in[0];
    const float* rot   = (const float*)d_in[1];
    const float* trans = (const float*)d_in[2];
    const float* pair  = (const float*)d_in[3];
    // d_in[4] = mask (all true) — no-op
    const float* lsg  = (const float*)d_in[5];
    const float* lsb  = (const float*)d_in[6];
    const float* lpg  = (const float*)d_in[7];
    const float* lpb  = (const float*)d_in[8];
    const float* wpb  = (const float*)d_in[9];
    const float* wqkv = (const float*)d_in[10];
    const float* pw   = (const float*)d_in[11];
    const float* wout = (const float*)d_in[12];
    const float* bout = (const float*)d_in[13];

    float* ws  = (float*)d_ws;
    float* NF  = ws + OFF_NF;
    float* QKV = ws + OFF_QKV;
    float* GQP = ws + OFF_GQP;
    float* GKP = ws + OFF_GKP;
    float* GVP = ws + OFF_GVP;
    float* Q2  = ws + OFF_Q2;
    float* K2A = ws + OFF_K2;
    float* Xc  = ws + OFF_X;

    ln_node_kernel<<<N_TOK, 64, 0, stream>>>(node, lsg, lsb, NF);
    gemm_nt<64,64,4,4,16><<<dim3(N_TOK/64, QKV_DIM/64), 256, 0, stream>>>(
        NF, wqkv, nullptr, QKV, N_TOK, QKV_DIM, NODE);
    prep_points<<<N_TOK, 256, 0, stream>>>(QKV, rot, trans, GQP, GKP, GVP, Q2, K2A);
    ipa_attn2<<<N_TOK/2, 512, 0, stream>>>(pair, lpg, lpb, wpb, pw, QKV,
                                           GQP, Q2, GKP, K2A, GVP, rot, trans, Xc);
    gemm_nt<32,32,2,2,32><<<dim3(N_TOK/32, NODE/32), 256, 0, stream>>>(
        Xc, wout, bout, (float*)d_out, N_TOK, NODE, OUT_CAT);
}